// Round 1
// baseline (914.021 us; speedup 1.0000x reference)
//
#include <hip/hip_runtime.h>

#define C_IN 256
#define HW   56
#define HW2  3136          // 56*56
#define SPAN 2304          // 9*256
#define TS   16
#define BKT  32
#define NBAT 16

// ---------------------------------------------------------------------------
// Kernel 1: compute hash index from first im2col column, gather 32 row ids.
// col0[p*256+c] = xp[0, c, i, j] = x[0, c, i-1, j-1]  (0 when i==0 or j==0)
// s = dot(a[0:2304], col0)/||col0|| + 0.5*sum(a[2304:2309])
// idx = ((int)fabsf(floorf(s))) % 16 ;  rows[b] = table[idx*32 + b]
// ---------------------------------------------------------------------------
__global__ void hash_rows_kernel(const float* __restrict__ x,
                                 const float* __restrict__ a,
                                 const int*   __restrict__ table,
                                 int*         __restrict__ rows_out) {
    __shared__ float rd[256];
    __shared__ float rn[256];
    const int t = threadIdx.x;
    float dv = 0.f, nq = 0.f;
    for (int k = t; k < SPAN; k += 256) {
        const int p = k >> 8;        // k / 256
        const int c = k & 255;       // k % 256
        const int i = p / 3, j = p % 3;
        float v = 0.f;
        if (i >= 1 && j >= 1) v = x[c * HW2 + (i - 1) * HW + (j - 1)];
        dv += a[k] * v;
        nq += v * v;
    }
    rd[t] = dv; rn[t] = nq;
    __syncthreads();
    for (int s = 128; s > 0; s >>= 1) {
        if (t < s) { rd[t] += rd[t + s]; rn[t] += rn[t + s]; }
        __syncthreads();
    }
    if (t == 0) {
        const float nrm = sqrtf(rn[0]);
        const float sv  = rd[0] / nrm
                        + 0.5f * (a[SPAN] + a[SPAN+1] + a[SPAN+2] + a[SPAN+3] + a[SPAN+4]);
        const int idx = ((int)fabsf(floorf(sv))) % TS;
        #pragma unroll
        for (int b = 0; b < BKT; ++b) rows_out[b] = table[idx * BKT + b];
    }
}

// ---------------------------------------------------------------------------
// Kernel 2: out[n, b, h, w] = 16 * sum_{p,c} K[rows[b], p*256+c] * xp[n,c,h+i,w+j]
// Block = 256 threads = 4 waves. Wave wg owns channels b = wg*8 .. wg*8+7.
// Lane owns one output column (64 consecutive spatial positions per block)
// -> fully coalesced x loads. Weights are wave-uniform (readfirstlane ->
// scalar loads), VALU does 8 FMA per x load.
// ---------------------------------------------------------------------------
__global__ __launch_bounds__(256, 4)
void alsh_conv_kernel(const float* __restrict__ x,
                      const float* __restrict__ kernels,
                      const int*   __restrict__ rows,
                      float*       __restrict__ out) {
    const int lane = threadIdx.x & 63;
    const int wg   = threadIdx.x >> 6;            // 0..3
    const int col  = (blockIdx.x << 6) + lane;    // 0..50175
    const int n    = col / HW2;
    const int s    = col - n * HW2;               // h*56 + w
    const int h    = s / HW;
    const int w    = s - h * HW;

    int rb[8];
    #pragma unroll
    for (int bb = 0; bb < 8; ++bb) {
        int r = rows[wg * 8 + bb];
        r = __builtin_amdgcn_readfirstlane(r);    // force SGPR -> scalar weight loads
        rb[bb] = r * SPAN;
    }

    float acc[8];
    #pragma unroll
    for (int bb = 0; bb < 8; ++bb) acc[bb] = 0.f;

    const float* xn = x + (size_t)n * (C_IN * HW2);

    for (int p = 0; p < 9; ++p) {
        const int di = p / 3 - 1, dj = p % 3 - 1;
        const int ih = h + di, iw = w + dj;
        const bool valid = ((unsigned)ih < (unsigned)HW) & ((unsigned)iw < (unsigned)HW);
        const float* xpp = xn + ih * HW + iw;     // + c*HW2 per channel
        const int kbase = p * C_IN;
        #pragma unroll 4
        for (int c = 0; c < C_IN; ++c) {
            const float xv = valid ? xpp[c * HW2] : 0.f;
            #pragma unroll
            for (int bb = 0; bb < 8; ++bb)
                acc[bb] += kernels[rb[bb] + kbase + c] * xv;
        }
    }

    float* o = out + (size_t)n * (BKT * HW2) + (size_t)(wg * 8) * HW2 + s;
    #pragma unroll
    for (int bb = 0; bb < 8; ++bb) o[bb * HW2] = 16.0f * acc[bb];
}

// ---------------------------------------------------------------------------
extern "C" void kernel_launch(void* const* d_in, const int* in_sizes, int n_in,
                              void* d_out, int out_size, void* d_ws, size_t ws_size,
                              hipStream_t stream) {
    const float* x       = (const float*)d_in[0];
    const float* kernels = (const float*)d_in[1];
    const float* a       = (const float*)d_in[2];
    const int*   table   = (const int*)d_in[3];
    float* out = (float*)d_out;
    int*   rows = (int*)d_ws;

    hipLaunchKernelGGL(hash_rows_kernel, dim3(1), dim3(256), 0, stream,
                       x, a, table, rows);

    const int ncols = NBAT * HW2;                 // 50176
    hipLaunchKernelGGL(alsh_conv_kernel, dim3(ncols / 64), dim3(256), 0, stream,
                       x, kernels, rows, out);
}

// Round 2
// 120.122 us; speedup vs baseline: 7.6091x; 7.6091x over previous
//
#include <hip/hip_runtime.h>
#include <stdint.h>

#define C_IN 256
#define HW   56
#define HW2  3136          // 56*56
#define SPAN 2304          // 9*256
#define TS   16
#define BKT  32
#define NBAT 16

typedef __attribute__((ext_vector_type(8))) short short8;
typedef __attribute__((ext_vector_type(4))) float f32x4;

// d_ws layout: [0..127]: rows (32 x int32). [512 ...]: Wpack ushort[73728] (147456 B)

// ---------------------------------------------------------------------------
// Kernel 1: hash -> 32 gathered row ids (unchanged from round 1, verified).
// ---------------------------------------------------------------------------
__global__ void hash_rows_kernel(const float* __restrict__ x,
                                 const float* __restrict__ a,
                                 const int*   __restrict__ table,
                                 int*         __restrict__ rows_out) {
    __shared__ float rd[256];
    __shared__ float rn[256];
    const int t = threadIdx.x;
    float dv = 0.f, nq = 0.f;
    for (int k = t; k < SPAN; k += 256) {
        const int p = k >> 8;
        const int c = k & 255;
        const int i = p / 3, j = p % 3;
        float v = 0.f;
        if (i >= 1 && j >= 1) v = x[c * HW2 + (i - 1) * HW + (j - 1)];
        dv += a[k] * v;
        nq += v * v;
    }
    rd[t] = dv; rn[t] = nq;
    __syncthreads();
    for (int s = 128; s > 0; s >>= 1) {
        if (t < s) { rd[t] += rd[t + s]; rn[t] += rn[t + s]; }
        __syncthreads();
    }
    if (t == 0) {
        const float nrm = sqrtf(rn[0]);
        const float sv  = rd[0] / nrm
                        + 0.5f * (a[SPAN] + a[SPAN+1] + a[SPAN+2] + a[SPAN+3] + a[SPAN+4]);
        const int idx = ((int)fabsf(floorf(sv))) % TS;
        #pragma unroll
        for (int b = 0; b < BKT; ++b) rows_out[b] = table[idx * BKT + b];
    }
}

// ---------------------------------------------------------------------------
// Kernel 2: build Wpack: gathered rows -> bf16, x16 scale folded in,
// pre-swizzled to A-fragment order.
// flat idx = (((q*2 + m)*4 + g)*16 + r)*8 + j
//   q = ccb*9 + p  (storage order matches GEMM loop: ccb outer, p inner)
//   k = p*256 + ccb*32 + 8*g + j ;  b = m*16 + r
// Lane (l) of the GEMM reads short8 at unit ((q*2+m)*4 + (l>>4))*16 + (l&15),
// giving A[row=l&15][k = 8*(l>>4)+j] for the 32-wide k-chunk q.
// ---------------------------------------------------------------------------
__global__ void build_wpack_kernel(const float* __restrict__ kernels,
                                   const int*   __restrict__ rows,
                                   unsigned short* __restrict__ wp) {
    const int idx = blockIdx.x * 256 + threadIdx.x;   // 0..73727
    const int j   = idx & 7;
    const int r   = (idx >> 3) & 15;
    const int g   = (idx >> 7) & 3;
    const int m   = (idx >> 9) & 1;
    const int q   = idx >> 10;          // 0..71
    const int p   = q % 9;
    const int ccb = q / 9;
    const int k   = p * 256 + ccb * 32 + 8 * g + j;
    const int b   = m * 16 + r;
    const int row = rows[b];
    const float v = kernels[(size_t)row * SPAN + k] * 16.0f;   // fold O/BUCKET scale
    unsigned u = __builtin_bit_cast(unsigned, v);
    u = (u + 0x7fffu + ((u >> 16) & 1u)) >> 16;                // RNE fp32->bf16
    wp[idx] = (unsigned short)u;
}

// ---------------------------------------------------------------------------
// Kernel 3: implicit-GEMM conv via mfma_f32_16x16x32_bf16.
// Wave owns 16 output columns (s) x all 32 output channels (2 M-tiles).
// B-frag: lane l supplies P[k=8*(l>>4)+j][s0+(l&15)] loaded straight from x
// (coalesced 64B per 16-lane group per j), converted fp32->bf16 in-register.
// K-loop: channel-block (32) outer, tap p inner -> 9-tap re-reads stay in L1.
// ---------------------------------------------------------------------------
__global__ __launch_bounds__(256, 4)
void alsh_mfma_kernel(const float* __restrict__ x,
                      const unsigned short* __restrict__ wp,
                      float* __restrict__ out) {
    int bid = blockIdx.x;                       // 0..783
    bid = (bid & 7) * 98 + (bid >> 3);          // XCD-chunked swizzle (784 = 8*98)

    const int lane = threadIdx.x & 63;
    const int wid  = threadIdx.x >> 6;
    const int c16  = lane & 15;                 // s-offset, A-row, D-col
    const int g    = lane >> 4;                 // 0..3
    const int s0   = bid * 64 + wid * 16;       // wave's base column
    const int n    = s0 / HW2;                  // uniform per wave (16 | 3136)
    const int sl   = (s0 - n * HW2) + c16;      // lane's spatial idx in image
    const int h    = sl / HW;
    const int w    = sl - h * HW;
    const float* xn = x + (size_t)n * (C_IN * HW2);
    const short8* wpv = (const short8*)wp;

    f32x4 acc0 = {0.f, 0.f, 0.f, 0.f};
    f32x4 acc1 = {0.f, 0.f, 0.f, 0.f};

    for (int ccb = 0; ccb < 8; ++ccb) {
        const int cc = ccb * 32;
        #pragma unroll 3
        for (int p = 0; p < 9; ++p) {
            const int q  = ccb * 9 + p;
            const int di = p / 3 - 1, dj = p % 3 - 1;
            const int ih = h + di, iw = w + dj;
            const bool ok = ((unsigned)ih < (unsigned)HW) & ((unsigned)iw < (unsigned)HW);
            const int voff = sl + di * HW + dj;

            const short8 a0 = wpv[((q * 2 + 0) * 4 + g) * 16 + c16];
            const short8 a1 = wpv[((q * 2 + 1) * 4 + g) * 16 + c16];

            short8 bf;
            #pragma unroll
            for (int j = 0; j < 8; ++j) {
                const int ch = cc + 8 * g + j;
                const float v = ok ? xn[(size_t)ch * HW2 + voff] : 0.f;
                const unsigned u = __builtin_bit_cast(unsigned, v);
                bf[j] = (short)((u + 0x8000u) >> 16);   // fp32->bf16 round-nearest
            }

            acc0 = __builtin_amdgcn_mfma_f32_16x16x32_bf16(a0, bf, acc0, 0, 0, 0);
            acc1 = __builtin_amdgcn_mfma_f32_16x16x32_bf16(a1, bf, acc1, 0, 0, 0);
        }
    }

    // C/D: col = lane&15 (= c16, already in sl), row = g*4 + reg
    float* ob = out + (size_t)n * (BKT * HW2) + sl;
    #pragma unroll
    for (int i = 0; i < 4; ++i) {
        const int b0 = g * 4 + i;
        ob[(size_t)b0 * HW2]        = acc0[i];
        ob[(size_t)(b0 + 16) * HW2] = acc1[i];
    }
}

// ---------------------------------------------------------------------------
extern "C" void kernel_launch(void* const* d_in, const int* in_sizes, int n_in,
                              void* d_out, int out_size, void* d_ws, size_t ws_size,
                              hipStream_t stream) {
    const float* x       = (const float*)d_in[0];
    const float* kernels = (const float*)d_in[1];
    const float* a       = (const float*)d_in[2];
    const int*   table   = (const int*)d_in[3];
    float* out = (float*)d_out;
    int*   rows = (int*)d_ws;
    unsigned short* wpack = (unsigned short*)((char*)d_ws + 512);

    hipLaunchKernelGGL(hash_rows_kernel, dim3(1), dim3(256), 0, stream,
                       x, a, table, rows);
    hipLaunchKernelGGL(build_wpack_kernel, dim3(288), dim3(256), 0, stream,
                       kernels, rows, wpack);
    hipLaunchKernelGGL(alsh_mfma_kernel, dim3(784), dim3(256), 0, stream,
                       x, wpack, out);
}